// Round 1
// baseline (217.912 us; speedup 1.0000x reference)
//
#include <hip/hip_runtime.h>
#include <math.h>

// B=2, T=2048, D=768, H=12, HD=64
typedef __attribute__((ext_vector_type(8))) __bf16 bf16x8;
typedef __attribute__((ext_vector_type(4))) __bf16 bf16x4;
typedef __attribute__((ext_vector_type(4))) float f32x4;

#define GLOAD_LDS16(gsrc, ldst) \
  __builtin_amdgcn_global_load_lds((__attribute__((address_space(1))) const void*)(gsrc), \
                                   (__attribute__((address_space(3))) void*)(ldst), 16, 0, 0)

__global__ void cvt_bf16_kernel(const float* __restrict__ in, __bf16* __restrict__ out, int n4) {
  int i = blockIdx.x * 256 + threadIdx.x;
  if (i < n4) {
    float4 f = ((const float4*)in)[i];
    bf16x4 o;
    o[0] = (__bf16)f.x; o[1] = (__bf16)f.y; o[2] = (__bf16)f.z; o[3] = (__bf16)f.w;
    ((bf16x4*)out)[i] = o;
  }
}

// out[C][R] = in[R][C]^T  (write-coalesced; strided reads served by L2/L3)
__global__ void cvtT_bf16_kernel(const float* __restrict__ in, __bf16* __restrict__ out, int R, int C) {
  int idx = blockIdx.x * 256 + threadIdx.x;
  if (idx < R * C) {
    int c = idx / R, r = idx - c * R;
    out[idx] = (__bf16)in[(size_t)r * C + c];
  }
}

// TN GEMM: C[M][N] = A[M][K] * B[N][K]^T (+bias). 128x128 tile, BK=64, 4 waves.
// LDS layout is fragment-major: segment (ks, tile16) holds 64 lanes x 16B, so
// ds_read addresses are lane-linear (conflict-free) and match global_load_lds's
// wave-base + lane*16 write pattern exactly (both-sides-linear, rule 21).
// EPI 0: qkv epilogue (bias, q-scale 0.125, scatter to [B,H,T,64] bf16)
// EPI 1: out-proj epilogue (bias, fp32 row-major to d_out)
template<int EPI>
__global__ __launch_bounds__(256)
void gemm_tn_kernel(const __bf16* __restrict__ A, const __bf16* __restrict__ Bm,
                    const float* __restrict__ bias, float* __restrict__ outF,
                    __bf16* __restrict__ qo, __bf16* __restrict__ ko, __bf16* __restrict__ vo,
                    int M, int N, int K) {
  const int lane = threadIdx.x & 63;
  const int wave = threadIdx.x >> 6;
  const int r16 = lane & 15, g = lane >> 4;
  const int mBase = blockIdx.y * 128, nBase = blockIdx.x * 128;
  __shared__ __align__(16) __bf16 lds[16384];  // 16KB A (segs 0..15) + 16KB B (segs 16..31)

  f32x4 acc[4][4];
#pragma unroll
  for (int i = 0; i < 4; ++i)
#pragma unroll
    for (int j = 0; j < 4; ++j) acc[i][j] = (f32x4){0.f, 0.f, 0.f, 0.f};

  const int mw = (wave >> 1) * 4;  // wave's first m 16-tile (of 8)
  const int nw = (wave & 1) * 4;   // wave's first n 16-tile (of 8)

  for (int kt = 0; kt < K; kt += 64) {
#pragma unroll
    for (int i = 0; i < 8; ++i) {
      int seg = wave * 8 + i;                 // 0..31
      int isB = seg >> 4, ks = (seg >> 3) & 1, t8 = seg & 7;
      int row = (isB ? nBase : mBase) + t8 * 16 + r16;
      const __bf16* src = (isB ? Bm : A) + (size_t)row * K + kt + ks * 32 + g * 8;
      GLOAD_LDS16(src, &lds[seg * 512]);      // wave-uniform LDS base
    }
    __syncthreads();
#pragma unroll
    for (int ks = 0; ks < 2; ++ks) {
      bf16x8 af[4], bf[4];
#pragma unroll
      for (int i = 0; i < 4; ++i) af[i] = *(const bf16x8*)&lds[((ks * 8 + mw + i) * 64 + lane) * 8];
#pragma unroll
      for (int j = 0; j < 4; ++j) bf[j] = *(const bf16x8*)&lds[((16 + ks * 8 + nw + j) * 64 + lane) * 8];
#pragma unroll
      for (int i = 0; i < 4; ++i)
#pragma unroll
        for (int j = 0; j < 4; ++j)
          acc[i][j] = __builtin_amdgcn_mfma_f32_16x16x32_bf16(af[i], bf[j], acc[i][j], 0, 0, 0);
    }
    __syncthreads();
  }

  // D-frag layout: col = lane&15, row = (lane>>4)*4 + e  [verified m89/m91]
#pragma unroll
  for (int i = 0; i < 4; ++i) {
#pragma unroll
    for (int j = 0; j < 4; ++j) {
      int c = nBase + (nw + j) * 16 + r16;
      float bb = bias[c];
#pragma unroll
      for (int e = 0; e < 4; ++e) {
        int r = mBase + (mw + i) * 16 + g * 4 + e;
        float val = acc[i][j][e] + bb;
        if (EPI == 0) {
          int which = c / 768;             // 0:q 1:k 2:v (block never straddles)
          int cc = c - which * 768;
          int hh = cc >> 6, dd = cc & 63;
          int bI = r >> 11, tt = r & 2047;
          size_t dst = (((size_t)(bI * 12 + hh)) * 2048 + tt) * 64 + dd;
          float sv = (which == 0) ? val * 0.125f : val;  // fold 1/sqrt(64) into q
          __bf16 bv = (__bf16)sv;
          if (which == 0) qo[dst] = bv;
          else if (which == 1) ko[dst] = bv;
          else vo[dst] = bv;
        } else {
          outF[(size_t)r * N + c] = val;
        }
      }
    }
  }
}

// Flash attention, causal. Grid (qt=T/64, B*H). 4 waves; wave w owns 16 q-rows.
__global__ __launch_bounds__(256)
void attn_kernel(const __bf16* __restrict__ qg, const __bf16* __restrict__ kg,
                 const __bf16* __restrict__ vg, __bf16* __restrict__ yatt) {
  const int qt = blockIdx.x, bh = blockIdx.y;
  const int lane = threadIdx.x & 63, wave = threadIdx.x >> 6;
  const int r16 = lane & 15, g = lane >> 4;
  const int bI = bh / 12, h = bh - bI * 12;
  const size_t headoff = (size_t)bh * 2048 * 64;
  const __bf16* Q = qg + headoff;
  const __bf16* Kh = kg + headoff;
  const __bf16* Vh = vg + headoff;

  __shared__ __align__(16) __bf16 Vt[64][72];        // V^T tile [d][k], pad 8
  __shared__ __align__(16) __bf16 Plds[4][16][72];   // per-wave P strip

  const int tq = qt * 64 + wave * 16 + r16;
  bf16x8 qf[2];
  qf[0] = *(const bf16x8*)&Q[(size_t)tq * 64 + g * 8];
  qf[1] = *(const bf16x8*)&Q[(size_t)tq * 64 + 32 + g * 8];

  f32x4 o[4];
#pragma unroll
  for (int j = 0; j < 4; ++j) o[j] = (f32x4){0.f, 0.f, 0.f, 0.f};
  float mrow[4], lrow[4];
#pragma unroll
  for (int e = 0; e < 4; ++e) { mrow[e] = -INFINITY; lrow[e] = 0.f; }

  for (int kt = 0; kt <= qt; ++kt) {
    __syncthreads();  // all PV reads of previous Vt done before overwrite
    {
      int kv = threadIdx.x >> 2, d0 = (threadIdx.x & 3) * 16;
      const __bf16* src = &Vh[((size_t)(kt * 64 + kv)) * 64 + d0];
      bf16x8 a0 = *(const bf16x8*)&src[0];
      bf16x8 a1 = *(const bf16x8*)&src[8];
#pragma unroll
      for (int i = 0; i < 8; ++i) Vt[d0 + i][kv] = a0[i];
#pragma unroll
      for (int i = 0; i < 8; ++i) Vt[d0 + 8 + i][kv] = a1[i];
    }
    // S = (Q*scale) K^T : contraction over d (contiguous for both) — K from global
    f32x4 s[4];
#pragma unroll
    for (int j = 0; j < 4; ++j) s[j] = (f32x4){0.f, 0.f, 0.f, 0.f};
#pragma unroll
    for (int ks = 0; ks < 2; ++ks) {
#pragma unroll
      for (int j = 0; j < 4; ++j) {
        int kc = kt * 64 + j * 16 + r16;
        bf16x8 kf = *(const bf16x8*)&Kh[(size_t)kc * 64 + ks * 32 + g * 8];
        s[j] = __builtin_amdgcn_mfma_f32_16x16x32_bf16(qf[ks], kf, s[j], 0, 0, 0);
      }
    }
    if (kt == qt) {  // causal mask on diagonal tile
#pragma unroll
      for (int j = 0; j < 4; ++j)
#pragma unroll
        for (int e = 0; e < 4; ++e)
          if (j * 16 + r16 > wave * 16 + g * 4 + e) s[j][e] = -INFINITY;
    }
    // online softmax (rows live in 16-lane groups; row = g*4+e, cols across lane&15 and j)
    float mt[4];
#pragma unroll
    for (int e = 0; e < 4; ++e) mt[e] = fmaxf(fmaxf(s[0][e], s[1][e]), fmaxf(s[2][e], s[3][e]));
#pragma unroll
    for (int off = 1; off < 16; off <<= 1)
#pragma unroll
      for (int e = 0; e < 4; ++e) mt[e] = fmaxf(mt[e], __shfl_xor(mt[e], off, 64));
    float alpha[4], ps[4];
#pragma unroll
    for (int e = 0; e < 4; ++e) {
      float mn = fmaxf(mrow[e], mt[e]);
      alpha[e] = __expf(mrow[e] - mn);   // exp(-inf)=0 on first tile
      mrow[e] = mn;
      ps[e] = 0.f;
    }
#pragma unroll
    for (int j = 0; j < 4; ++j)
#pragma unroll
      for (int e = 0; e < 4; ++e) {
        float p = __expf(s[j][e] - mrow[e]);  // masked: exp(-inf)=0
        s[j][e] = p;
        ps[e] += p;
      }
#pragma unroll
    for (int off = 1; off < 16; off <<= 1)
#pragma unroll
      for (int e = 0; e < 4; ++e) ps[e] += __shfl_xor(ps[e], off, 64);
#pragma unroll
    for (int e = 0; e < 4; ++e) lrow[e] = lrow[e] * alpha[e] + ps[e];
#pragma unroll
    for (int j = 0; j < 4; ++j)
#pragma unroll
      for (int e = 0; e < 4; ++e) o[j][e] *= alpha[e];
    // P (D-layout) -> LDS, re-read as A-fragments
#pragma unroll
    for (int j = 0; j < 4; ++j)
#pragma unroll
      for (int e = 0; e < 4; ++e)
        Plds[wave][g * 4 + e][j * 16 + r16] = (__bf16)s[j][e];
    __syncthreads();  // Vt staged by all threads; own-wave Plds ordered by lgkmcnt
#pragma unroll
    for (int ks = 0; ks < 2; ++ks) {
      bf16x8 pf = *(const bf16x8*)&Plds[wave][r16][ks * 32 + g * 8];
#pragma unroll
      for (int dj = 0; dj < 4; ++dj) {
        bf16x8 vf = *(const bf16x8*)&Vt[dj * 16 + r16][ks * 32 + g * 8];
        o[dj] = __builtin_amdgcn_mfma_f32_16x16x32_bf16(pf, vf, o[dj], 0, 0, 0);
      }
    }
  }
#pragma unroll
  for (int dj = 0; dj < 4; ++dj)
#pragma unroll
    for (int e = 0; e < 4; ++e) {
      float val = o[dj][e] / lrow[e];
      int t = qt * 64 + wave * 16 + g * 4 + e;
      yatt[((size_t)(bI * 2048 + t)) * 768 + h * 64 + dj * 16 + r16] = (__bf16)val;
    }
}

extern "C" void kernel_launch(void* const* d_in, const int* in_sizes, int n_in,
                              void* d_out, int out_size, void* d_ws, size_t ws_size,
                              hipStream_t stream) {
  (void)in_sizes; (void)n_in; (void)out_size; (void)ws_size;
  const float* x     = (const float*)d_in[0];
  const float* w_qkv = (const float*)d_in[1];
  const float* b_qkv = (const float*)d_in[2];
  const float* w_out = (const float*)d_in[3];
  const float* b_out = (const float*)d_in[4];
  float* out = (float*)d_out;

  char* ws = (char*)d_ws;
  __bf16* xb    = (__bf16*)(ws);              // [4096][768]          6,291,456 B
  __bf16* wqkvT = (__bf16*)(ws + 6291456);    // [2304][768]          3,538,944 B
  __bf16* woT   = (__bf16*)(ws + 9830400);    // [768][768]           1,179,648 B
  __bf16* qb    = (__bf16*)(ws + 11010048);   // [B,H,T,64]           6,291,456 B
  __bf16* kb    = (__bf16*)(ws + 17301504);
  __bf16* vb    = (__bf16*)(ws + 23592960);
  __bf16* yatt  = (__bf16*)(ws + 29884416);   // [4096][768]

  cvt_bf16_kernel<<<3072, 256, 0, stream>>>(x, xb, 786432);                       // 4096*768/4
  cvtT_bf16_kernel<<<6912, 256, 0, stream>>>(w_qkv, wqkvT, 768, 2304);
  cvtT_bf16_kernel<<<2304, 256, 0, stream>>>(w_out, woT, 768, 768);
  gemm_tn_kernel<0><<<dim3(18, 32), 256, 0, stream>>>(xb, wqkvT, b_qkv, nullptr,
                                                      qb, kb, vb, 4096, 2304, 768);
  attn_kernel<<<dim3(32, 24), 256, 0, stream>>>(qb, kb, vb, yatt);
  gemm_tn_kernel<1><<<dim3(6, 32), 256, 0, stream>>>(yatt, woT, b_out, out,
                                                     nullptr, nullptr, nullptr, 4096, 768, 768);
}